// Round 16
// baseline (325.881 us; speedup 1.0000x reference)
//
#include <hip/hip_runtime.h>
#include <math.h>

#define B_ 8
#define N_ 4096
#define C_ 512
#define H_ 8
#define D_ 64
#define M_ 16
#define BN_TOK (B_*N_)
#define TAU_ 0.1f

typedef short s8v __attribute__((ext_vector_type(8)));
typedef float f4v __attribute__((ext_vector_type(4)));
typedef unsigned short u16;

__device__ __forceinline__ float wave_reduce_sum(float v){
  #pragma unroll
  for (int o = 32; o > 0; o >>= 1) v += __shfl_xor(v, o);
  return v;
}

__device__ __forceinline__ unsigned short f2b(float f){
  unsigned int u = __float_as_uint(f);
  u += 0x7fffu + ((u >> 16) & 1u);           // RNE
  return (unsigned short)(u >> 16);
}

__device__ __forceinline__ float b2f(u16 b){
  return __uint_as_float(((unsigned int)b) << 16);
}

__device__ __forceinline__ s8v pack8(const float* f){
  s8v r;
  #pragma unroll
  for (int e = 0; e < 8; ++e) r[e] = (short)f2b(f[e]);
  return r;
}

// async 16B global -> LDS (linear dest: wave-uniform base + lane*16)
__device__ __forceinline__ void gload16(const u16* g, u16* l){
  __builtin_amdgcn_global_load_lds(
      (const __attribute__((address_space(1))) unsigned int*)g,
      (__attribute__((address_space(3))) unsigned int*)l, 16, 0, 0);
}

// ---------------- merged one-time conversions ----------------
__global__ __launch_bounds__(256) void prep_all(const float* __restrict__ x, u16* __restrict__ xb,
                                                const float* __restrict__ W_qkv,
                                                const float* __restrict__ W_rspec,
                                                const float* __restrict__ W_rspat,
                                                const float* __restrict__ W_proj,
                                                u16* __restrict__ Wqk,
                                                u16* __restrict__ Wt_v,
                                                u16* __restrict__ Wt_r,
                                                u16* __restrict__ Wt_p){
  const int bid = blockIdx.x;
  const int t = threadIdx.x;
  if (bid < 1024) {
    const int n8 = (BN_TOK*C_)/8;
    for (int i = bid * 256 + t; i < n8; i += 1024*256) {
      const float4* p = (const float4*)(x + (size_t)i * 8);
      float4 a = p[0], b = p[1];
      float f[8] = {a.x,a.y,a.z,a.w,b.x,b.y,b.z,b.w};
      *(s8v*)(xb + (size_t)i * 8) = pack8(f);
    }
    return;
  }
  if (bid < 1536) {                       // Wq k-major: Wqk[k][hd] = W_qkv[k][hd]
    const int k = bid - 1024;
    Wqk[(size_t)k*512 + t]       = f2b(W_qkv[(size_t)k*1536 + t]);
    Wqk[(size_t)k*512 + t + 256] = f2b(W_qkv[(size_t)k*1536 + t + 256]);
    return;
  }
  const int r = bid - 1536;
  const float* src; int ld, coff, n; u16* dst;
  if (r < 512)       { src = W_qkv;   ld = 1536; coff = 1024; n = r;        dst = Wt_v; }
  else if (r < 640)  { src = W_rspec; ld = 128;  coff = 0;    n = r - 512;  dst = Wt_r; }
  else if (r < 768)  { src = W_rspat; ld = 128;  coff = 0;    n = r - 640;  dst = Wt_r + 128*512; }
  else               { src = W_proj;  ld = 512;  coff = 0;    n = r - 768;  dst = Wt_p; }
  dst[(size_t)n*512 + t]       = f2b(src[(size_t)t*ld + coff + n]);
  dst[(size_t)n*512 + t + 256] = f2b(src[(size_t)(t+256)*ld + coff + n]);
}

// ====== bf16 GEMM, B pre-transposed: C[M,N] = A[M,K] * Bt[N,K]^T (+bias) ======
// 256x128 tile, 512 threads (8 waves, 4Mx2N wave grid), BK=64 depth-2
// counted-vmcnt pipeline (same sync structure + swizzle formulas as the proven
// 128^2 version; tile-size-only change). LDS: A 64KB + B 32KB = 96KB, 1 blk/CU.
// Per K-step: 256 MFMA/block against 2 barriers (4x the 128^2 amortization).
// MODE 0: f32 out (+bias). MODE 1: bf16 out.
// MODE 2: split — block cols < split -> bf16 C (ldc); >= split -> bf16 C2 (ldc2, col-split).
template<int MODE>
__global__ __launch_bounds__(512) void gemm_bt(const u16* __restrict__ A,
                                               const u16* __restrict__ Bt,
                                               const float* __restrict__ bias,
                                               void* __restrict__ C,
                                               u16* __restrict__ C2,
                                               int K, int lda, int ldc, int ldc2,
                                               int split, int bt_bstride) {
  __shared__ __align__(16) u16 Asm[2][2][256*32];   // [depth][khalf] 64 KB
  __shared__ __align__(16) u16 Bsm[2][2][128*32];   // [depth][khalf] 32 KB
  const int tid = threadIdx.x;
  const int lane = tid & 63, w = tid >> 6;          // 8 waves
  const int bm = blockIdx.x * 256, bn = blockIdx.y * 128;

  const int lrow = lane >> 2;
  const int kch  = ((lane & 3) ^ ((lane >> 3) & 3)) << 3;   // pre-swizzled k-chunk

  const u16* Btb = Bt + (size_t)(bm >> 12) * bt_bstride;    // per-batch B (4096 rows/batch)
  // staging: 8 waves cover 128 rows per gload16 (rows w*16+lrow); A needs 2 row-halves
  const u16* Ag0 = A   + (size_t)(bm + w*16 + lrow) * lda + kch;
  const u16* Ag1 = Ag0 + (size_t)128 * lda;
  const u16* Bg0 = Btb + (size_t)(bn + w*16 + lrow) * K + kch;
  const int la0 = (w*16)*32, la1 = (w*16+128)*32;
  const int lb0 = (w*16)*32;

  const int lm = lane & 15, lg = lane >> 4;
  const int wr = w >> 1, wc = w & 1;                // wave grid 4M x 2N
  const int w0 = wr * 64;                           // wave row base (A)
  const int c0 = wc * 64;                           // wave col base (B)
  const int xs = (lg ^ ((lm >> 1) & 3)) << 3;       // read-side swizzle slot

  const int NSTEP = K >> 6;                          // 64 k per step

  f4v acc[4][4];
  #pragma unroll
  for (int i = 0; i < 4; ++i)
    #pragma unroll
    for (int j = 0; j < 4; ++j) acc[i][j] = (f4v){0.f,0.f,0.f,0.f};

  #define STAGE(buf, tt)                                        \
    gload16(Ag0 + (tt)*64,      &Asm[buf][0][la0]);             \
    gload16(Ag1 + (tt)*64,      &Asm[buf][0][la1]);             \
    gload16(Ag0 + (tt)*64 + 32, &Asm[buf][1][la0]);             \
    gload16(Ag1 + (tt)*64 + 32, &Asm[buf][1][la1]);             \
    gload16(Bg0 + (tt)*64,      &Bsm[buf][0][lb0]);             \
    gload16(Bg0 + (tt)*64 + 32, &Bsm[buf][1][lb0]);

  STAGE(0, 0)
  STAGE(1, 1)

  int cur = 0;
  for (int k = 0; k < NSTEP; ++k) {
    // wait own tile's 6 loads; the other tile's 6 stay in flight
    if (k < NSTEP - 1) asm volatile("s_waitcnt vmcnt(6)" ::: "memory");
    else               asm volatile("s_waitcnt vmcnt(0)" ::: "memory");
    __builtin_amdgcn_s_barrier();            // raw: no vmcnt(0) drain
    __builtin_amdgcn_sched_barrier(0);       // no ds_read hoist above barrier

    #pragma unroll
    for (int h = 0; h < 2; ++h) {
      s8v bf_[4];
      #pragma unroll
      for (int j = 0; j < 4; ++j) bf_[j] = *(const s8v*)&Bsm[cur][h][(c0 + 16*j + lm)*32 + xs];
      #pragma unroll
      for (int i = 0; i < 4; ++i) {
        s8v af = *(const s8v*)&Asm[cur][h][(w0 + 16*i + lm)*32 + xs];
        #pragma unroll
        for (int j = 0; j < 4; ++j)
          acc[i][j] = __builtin_amdgcn_mfma_f32_16x16x32_bf16(af, bf_[j], acc[i][j], 0, 0, 0);
      }
    }

    __builtin_amdgcn_sched_barrier(0);       // reads complete before barrier in program order
    __builtin_amdgcn_s_barrier();            // all waves done reading buf[cur]
    if (k + 2 < NSTEP) {
      STAGE(cur, k + 2)
    }
    __builtin_amdgcn_sched_barrier(0);       // stages issue before next vmcnt counts them
    cur ^= 1;
  }
  #undef STAGE

  #pragma unroll
  for (int j = 0; j < 4; ++j) {
    const int col = bn + c0 + 16*j + lm;
    const float bj = (MODE == 0 && bias) ? bias[col] : 0.f;
    #pragma unroll
    for (int i = 0; i < 4; ++i) {
      const int row = bm + w0 + 16*i + 4*lg;
      #pragma unroll
      for (int r = 0; r < 4; ++r) {
        if (MODE == 2 && bn >= split)
          C2[(size_t)(row + r) * ldc2 + (col - split)] = f2b(acc[i][j][r]);
        else if (MODE == 1 || MODE == 2)
          ((u16*)C)[(size_t)(row + r) * ldc + col] = f2b(acc[i][j][r]);
        else
          ((float*)C)[(size_t)(row + r) * ldc + col] = acc[i][j][r] + bj;
      }
    }
  }
}

// ---------------- router top-k + masked softmax (bf16 logits in, bf16 r out) ----------------
__global__ __launch_bounds__(256) void router_topk(const u16* __restrict__ logits,
                            const float* __restrict__ b_rspec, const float* __restrict__ b_rspat,
                            u16* __restrict__ rb_spec, u16* __restrict__ rb_spat) {
  int t = blockIdx.x * blockDim.x + threadIdx.x;
  if (t >= BN_TOK * H_ * 2) return;
  int route = t & 1, h = (t >> 1) & 7, bn = t >> 4;
  int b = bn >> 12, n = bn & 4095;
  const u16* lg = logits + (size_t)bn*256 + route*128 + h*16;
  const float* bias = (route ? b_rspat : b_rspec) + h*16;
  float v[16];
  #pragma unroll
  for (int m=0;m<16;++m) v[m] = b2f(lg[m]) + bias[m];
  float m1=-1e30f, m2=-1e30f, m3=-1e30f;
  #pragma unroll
  for (int m=0;m<16;++m){
    float x=v[m];
    if (x>m1){m3=m2;m2=m1;m1=x;}
    else if (x>m2){m3=m2;m2=x;}
    else if (x>m3){m3=x;}
  }
  float S=0.f, Sm=0.f, e[16];
  #pragma unroll
  for (int m=0;m<16;++m){ e[m]=expf(v[m]-m1); S+=e[m]; if (v[m]>=m3) Sm+=e[m]; }
  float denom = fmaxf(Sm/S, 1e-6f);
  float inv = 1.f/(S*denom);
  size_t idx = (((size_t)b*H_ + h)*N_ + n)*16;
  u16* rb  = (route ? rb_spat : rb_spec) + idx;
  #pragma unroll
  for (int m=0;m<16;++m) {
    float val = (v[m] >= m3) ? e[m]*inv : 0.f;
    rb[m] = f2b(val);
  }
}

// ------- context via MFMA: per (b,h,chunk of 256 tokens); V from vb [tok][512]; pctx bf16 -------
__global__ __launch_bounds__(256) void context_mfma(const u16* __restrict__ rb_spec, const u16* __restrict__ rb_spat,
                               const float* __restrict__ K_spec, const float* __restrict__ K_spat,
                               const u16* __restrict__ vb, u16* __restrict__ pctx, float* __restrict__ pZ) {
  const int chunk = blockIdx.x & 15, bh = blockIdx.x >> 4;
  const int b = bh >> 3, h = bh & 7;
  const int tid = threadIdx.x;
  const int lane = tid & 63, w = tid >> 6;
  const int lm = lane & 15, lg = lane >> 4;

  __shared__ __align__(16) unsigned short Kc[64*32];   // B1: [d][k=32] swz4
  __shared__ __align__(16) unsigned short Rs[64*32];   // A1: [n][k=32] swz4
  __shared__ __align__(16) unsigned short Vt[64*64];   // A2: [e][n]    swz8
  __shared__ __align__(16) unsigned short Ps[64*64];   // B2: [d][n]    swz8
  __shared__ float Zs[256];

  {
    int d = tid & 63, c = tid >> 6;
    float f[8];
    #pragma unroll
    for (int u = 0; u < 8; ++u) {
      int k = c*8 + u;
      f[u] = (k < 16) ? K_spec[h*1024 + k*64 + d] : K_spat[h*1024 + (k-16)*64 + d];
    }
    *(s8v*)&Kc[d*32 + ((c ^ (d&3)) << 3)] = pack8(f);
  }

  const u16* rsg = rb_spec + ((size_t)bh*N_ + chunk*256)*16;
  const u16* rtg = rb_spat + ((size_t)bh*N_ + chunk*256)*16;
  const u16* vbase = vb + h*64;
  const size_t tokbase = (size_t)b*N_ + chunk*256;

  f4v acc2[4];
  #pragma unroll
  for (int j = 0; j < 4; ++j) acc2[j] = (f4v){0.f,0.f,0.f,0.f};
  float zreg[4] = {0.f,0.f,0.f,0.f};

  for (int t0 = 0; t0 < 4; ++t0) {
    __syncthreads();
    {
      int n = tid & 63, c = tid >> 6;
      const u16* src = (c < 2 ? rsg : rtg) + ((size_t)(t0*64 + n))*16 + (c&1)*8;
      *(s8v*)&Rs[n*32 + ((c ^ (n&3)) << 3)] = *(const s8v*)src;
    }
    {
      int n = tid & 63, eq = tid >> 6;
      const u16* src = vbase + (tokbase + t0*64 + n)*512 + eq*16;
      u16 f[16];
      *(s8v*)&f[0] = ((const s8v*)src)[0];
      *(s8v*)&f[8] = ((const s8v*)src)[1];
      #pragma unroll
      for (int u = 0; u < 16; ++u) {
        int e = eq*16 + u;
        Vt[e*64 + ((((n>>3) ^ (e&7)) << 3) | (n&7))] = f[u];
      }
    }
    __syncthreads();
    {
      s8v a1 = *(const s8v*)&Rs[(16*w + lm)*32 + ((lg ^ (lm&3)) << 3)];
      #pragma unroll
      for (int j = 0; j < 4; ++j) {
        s8v b1 = *(const s8v*)&Kc[(16*j + lm)*32 + ((lg ^ (lm&3)) << 3)];
        f4v c1 = (f4v){0.f,0.f,0.f,0.f};
        c1 = __builtin_amdgcn_mfma_f32_16x16x32_bf16(a1, b1, c1, 0, 0, 0);
        float p0 = expf(c1[0]), p1 = expf(c1[1]), p2 = expf(c1[2]), p3 = expf(c1[3]);
        float zz = p0 + p1 + p2 + p3;
        zz += __shfl_xor(zz, 16); zz += __shfl_xor(zz, 32);
        zreg[j] += zz;
        int d = 16*j + lm;
        int n0w = 16*w + 4*lg;
        Ps[d*64 + (((((n0w  )>>3) ^ (d&7)) << 3) | ((n0w  )&7))] = f2b(p0);
        Ps[d*64 + (((((n0w+1)>>3) ^ (d&7)) << 3) | ((n0w+1)&7))] = f2b(p1);
        Ps[d*64 + (((((n0w+2)>>3) ^ (d&7)) << 3) | ((n0w+2)&7))] = f2b(p2);
        Ps[d*64 + (((((n0w+3)>>3) ^ (d&7)) << 3) | ((n0w+3)&7))] = f2b(p3);
      }
    }
    __syncthreads();
    #pragma unroll
    for (int kb = 0; kb < 2; ++kb) {
      s8v a2 = *(const s8v*)&Vt[(16*w + lm)*64 + (((kb*4 + lg) ^ (lm&7)) << 3)];
      #pragma unroll
      for (int j = 0; j < 4; ++j) {
        s8v b2 = *(const s8v*)&Ps[(16*j + lm)*64 + (((kb*4 + lg) ^ (lm&7)) << 3)];
        acc2[j] = __builtin_amdgcn_mfma_f32_16x16x32_bf16(a2, b2, acc2[j], 0, 0, 0);
      }
    }
  }
  u16* pc = pctx + (size_t)(bh*16 + chunk)*4096;
  #pragma unroll
  for (int j = 0; j < 4; ++j) {
    #pragma unroll
    for (int r = 0; r < 4; ++r)
      pc[(16*w + 4*lg + r)*64 + 16*j + lm] = f2b(acc2[j][r]);
    if (lg == 0) Zs[w*64 + 16*j + lm] = zreg[j];
  }
  __syncthreads();
  if (tid < 64)
    pZ[(size_t)(bh*16 + chunk)*64 + tid] = Zs[tid] + Zs[64+tid] + Zs[128+tid] + Zs[192+tid];
}

// ---- reduce partials: ctx^T[e][d] = sum_c pctx / Z[d] (1 output/thread; pctx bf16) ----
__global__ __launch_bounds__(256) void context_reduce(const u16* __restrict__ pctx, const float* __restrict__ pZ,
                              float* __restrict__ ctx) {
  const int gid = blockIdx.x * 256 + threadIdx.x;
  const int bh = gid >> 12, e = (gid >> 6) & 63, d = gid & 63;
  float z = 0.f, s = 0.f;
  for (int c = 0; c < 16; ++c) {
    z += pZ[(size_t)(bh*16 + c)*64 + d];
    s += b2f(pctx[(size_t)(bh*16 + c)*4096 + e*64 + d]);
  }
  ctx[(size_t)bh*4096 + e*64 + d] = s / z;
}

// ---- CW precompute: CWt[b][c][h*64+d] = sum_e ctx^T[bh][e][d] * Wp[h*64+e][c] ----
__global__ __launch_bounds__(256) void cwt_kernel(const float* __restrict__ ctx, const u16* __restrict__ Wt_p,
                                                  u16* __restrict__ CWt) {
  const int bh = blockIdx.x >> 3, oct = blockIdx.x & 7;
  const int b = bh >> 3, h = bh & 7;
  const int tid = threadIdx.x;
  __shared__ float ctxS[64*64];       // [e][d]
  __shared__ u16 WsL[64*64];          // [c_local][e]
  {
    int e = tid >> 2, dq = tid & 3;
    const float4* src = (const float4*)(ctx + (size_t)bh*4096 + e*64 + dq*16);
    float4* dst = (float4*)(ctxS + e*64 + dq*16);
    dst[0] = src[0]; dst[1] = src[1]; dst[2] = src[2]; dst[3] = src[3];
  }
  const int c0 = oct * 64;
  {
    int cl = tid >> 2, eq = tid & 3;
    const s8v* src = (const s8v*)(Wt_p + (size_t)(c0 + cl)*512 + h*64 + eq*16);
    *(s8v*)&WsL[cl*64 + eq*16]     = src[0];
    *(s8v*)&WsL[cl*64 + eq*16 + 8] = src[1];
  }
  __syncthreads();
  const int d = tid & 63, cq = tid >> 6;
  for (int ci = 0; ci < 16; ++ci) {
    int cl = cq*16 + ci;
    float acc = 0.f;
    #pragma unroll
    for (int e = 0; e < 64; ++e)
      acc = fmaf(ctxS[e*64 + d], b2f(WsL[cl*64 + e]), acc);
    CWt[((size_t)b*512 + (c0 + cl))*512 + h*64 + d] = f2b(acc);
  }
}

// ---------------- normalized prototypes + diversity (merged grid) ----------------
__global__ __launch_bounds__(64) void protnorm_div(const float* __restrict__ K_spec, const float* __restrict__ K_spat,
                               const float* __restrict__ W_prot, const float* __restrict__ b_prot,
                               float* __restrict__ pnorm, float* __restrict__ pdiv) {
  const int bid = blockIdx.x;
  const int e = threadIdx.x;
  if (bid < 256) {
    int route = bid >> 7, hm = bid & 127;
    const float* Km = (route ? K_spat : K_spec) + hm*64;
    __shared__ float kv[64];
    kv[e] = Km[e];
    __syncthreads();
    float acc = b_prot[e];
    for (int dcol = 0; dcol < 64; ++dcol) acc = fmaf(kv[dcol], W_prot[dcol*64 + e], acc);
    float n2 = wave_reduce_sum(acc*acc);
    pnorm[(size_t)bid*64 + e] = acc / fmaxf(sqrtf(n2), 1e-12f);
    return;
  }
  const int db = bid - 256;                 // 0..15
  int route = db >> 3, h = db & 7;
  const float* Km = (route ? K_spat : K_spec) + h*16*64;
  float s = 0.f, selfsum = 0.f;
  for (int m = 0; m < 16; ++m) {
    float x = Km[m*64 + e];
    float n2 = wave_reduce_sum(x*x);
    float p = x / fmaxf(sqrtf(n2), 1e-6f);
    s += p; selfsum += p*p;
  }
  float off = wave_reduce_sum(s*s - selfsum);
  if (e == 0) pdiv[db] = off;
}

// ---------------- contrastive loss via MFMA (per-block partials, NO atomics; r from bf16) ----------------
__global__ __launch_bounds__(256) void contrastive_mfma(const u16* __restrict__ vb,
                                   const u16* __restrict__ rb_spec, const u16* __restrict__ rb_spat,
                                   const float* __restrict__ W_tok, const float* __restrict__ b_tok,
                                   const float* __restrict__ pnorm, float* __restrict__ pcontr) {
  const int tile = blockIdx.x & 255;
  const int h = blockIdx.x >> 8;
  const int t0 = tile * 128;
  const int b = t0 >> 12;
  const int n0 = t0 & 4095;
  const int tid = threadIdx.x;
  const int lane = tid & 63, w = tid >> 6;
  const int lm = lane & 15, lg = lane >> 4;

  __shared__ __align__(16) unsigned short Usm[128*72];   // V / T / S overlay (18 KB)
  __shared__ __align__(16) unsigned short Wsm[64*72];
  __shared__ __align__(16) unsigned short Psm[32*72];
  __shared__ float nrmS[128];
  __shared__ float btkS[64];
  __shared__ float bred[2][4];
  float* Uf = (float*)Usm;                               // S view: row stride 36 f32

  {
    const int vr = tid >> 1, vh = tid & 1;
    const u16* vg = vb + (size_t)(b*N_ + n0 + vr)*512 + h*64 + vh*32;
    #pragma unroll
    for (int c = 0; c < 4; ++c) *(s8v*)&Usm[vr*72 + vh*32 + c*8] = ((const s8v*)vg)[c];
  }
  {
    const int e = tid & 63, kh = tid >> 6;
    float f[16];
    #pragma unroll
    for (int rr = 0; rr < 16; ++rr) f[rr] = W_tok[(size_t)(kh*16+rr)*64 + e];
    *(s8v*)&Wsm[e*72 + kh*16]     = pack8(&f[0]);
    *(s8v*)&Wsm[e*72 + kh*16 + 8] = pack8(&f[8]);
  }
  if (tid < 128) {
    const int proto = tid >> 2, q4 = tid & 3;
    const int src = (proto < 16) ? (h*16 + proto) : (128 + h*16 + (proto-16));
    const float* pg = pnorm + (size_t)src*64 + q4*16;
    float f[16];
    #pragma unroll
    for (int i = 0; i < 4; ++i) {
      float4 v4 = ((const float4*)pg)[i];
      f[4*i]=v4.x; f[4*i+1]=v4.y; f[4*i+2]=v4.z; f[4*i+3]=v4.w;
    }
    *(s8v*)&Psm[proto*72 + q4*16]     = pack8(&f[0]);
    *(s8v*)&Psm[proto*72 + q4*16 + 8] = pack8(&f[8]);
  }
  if (tid < 64) btkS[tid] = b_tok[tid];
  __syncthreads();

  f4v acc[2][4];
  #pragma unroll
  for (int i=0;i<2;++i)
    #pragma unroll
    for (int j=0;j<4;++j) acc[i][j] = (f4v){0.f,0.f,0.f,0.f};
  {
    s8v bf0[4], bf1[4];
    #pragma unroll
    for (int j=0;j<4;++j) {
      bf0[j] = *(const s8v*)&Wsm[(j*16+lm)*72 + lg*8];
      bf1[j] = *(const s8v*)&Wsm[(j*16+lm)*72 + 32 + lg*8];
    }
    #pragma unroll
    for (int i=0;i<2;++i) {
      s8v af0 = *(const s8v*)&Usm[(w*32+16*i+lm)*72 + lg*8];
      s8v af1 = *(const s8v*)&Usm[(w*32+16*i+lm)*72 + 32 + lg*8];
      #pragma unroll
      for (int j=0;j<4;++j) {
        acc[i][j] = __builtin_amdgcn_mfma_f32_16x16x32_bf16(af0, bf0[j], acc[i][j], 0, 0, 0);
        acc[i][j] = __builtin_amdgcn_mfma_f32_16x16x32_bf16(af1, bf1[j], acc[i][j], 0, 0, 0);
      }
    }
  }
  #pragma unroll
  for (int i=0;i<2;++i) {
    #pragma unroll
    for (int r=0;r<4;++r) {
      float s = 0.f;
      #pragma unroll
      for (int j=0;j<4;++j) {
        float val = acc[i][j][r] + btkS[j*16+lm];
        acc[i][j][r] = val;
        s += val*val;
      }
      s += __shfl_xor(s,1); s += __shfl_xor(s,2); s += __shfl_xor(s,4); s += __shfl_xor(s,8);
      if (lm == 0) nrmS[w*32 + 16*i + lg*4 + r] = s;
    }
  }
  #pragma unroll
  for (int i=0;i<2;++i)
    #pragma unroll
    for (int j=0;j<4;++j)
      #pragma unroll
      for (int r=0;r<4;++r)
        Usm[(w*32+16*i+lg*4+r)*72 + j*16+lm] = f2b(acc[i][j][r]);
  __syncthreads();

  f4v acc2[2][2];
  #pragma unroll
  for (int i=0;i<2;++i)
    #pragma unroll
    for (int j=0;j<2;++j) acc2[i][j] = (f4v){0.f,0.f,0.f,0.f};
  {
    s8v bf0[2], bf1[2];
    #pragma unroll
    for (int j=0;j<2;++j) {
      bf0[j] = *(const s8v*)&Psm[(j*16+lm)*72 + lg*8];
      bf1[j] = *(const s8v*)&Psm[(j*16+lm)*72 + 32 + lg*8];
    }
    #pragma unroll
    for (int i=0;i<2;++i) {
      s8v af0 = *(const s8v*)&Usm[(w*32+16*i+lm)*72 + lg*8];
      s8v af1 = *(const s8v*)&Usm[(w*32+16*i+lm)*72 + 32 + lg*8];
      #pragma unroll
      for (int j=0;j<2;++j) {
        acc2[i][j] = __builtin_amdgcn_mfma_f32_16x16x32_bf16(af0, bf0[j], acc2[i][j], 0, 0, 0);
        acc2[i][j] = __builtin_amdgcn_mfma_f32_16x16x32_bf16(af1, bf1[j], acc2[i][j], 0, 0, 0);
      }
    }
  }
  #pragma unroll
  for (int i=0;i<2;++i)
    #pragma unroll
    for (int j=0;j<2;++j)
      #pragma unroll
      for (int r=0;r<4;++r)
        Uf[(w*32+16*i+lg*4+r)*36 + j*16+lm] = acc2[i][j][r];
  __syncthreads();

  float l = 0.f;
  {
    const int tt = tid >> 1, route = tid & 1;
    float inv = 1.f / fmaxf(sqrtf(nrmS[tt]), 1e-12f);
    const u16* rg = (route ? rb_spat : rb_spec) + (((size_t)b*H_ + h)*N_ + n0 + tt)*16;
    float s0[16];
    #pragma unroll
    for (int m=0;m<16;++m) s0[m] = Uf[tt*36 + route*16 + m]*inv;
    float pos = 0.f, mx = -1e30f;
    #pragma unroll
    for (int m=0;m<16;++m) {
      pos += s0[m]*b2f(rg[m]);
      mx = fmaxf(mx, s0[m]);
    }
    float z = 0.f;
    #pragma unroll
    for (int m=0;m<16;++m) z += expf((s0[m]-mx)/TAU_);
    l = pos/TAU_ - (mx/TAU_ + logf(z));
  }
  float lspec = (tid & 1) ? 0.f : l;
  float lspat = (tid & 1) ? l : 0.f;
  lspec = wave_reduce_sum(lspec);
  lspat = wave_reduce_sum(lspat);
  if (lane == 0) { bred[0][w]=lspec; bred[1][w]=lspat; }
  __syncthreads();
  if (tid == 0) {
    pcontr[2*blockIdx.x]     = bred[0][0]+bred[0][1]+bred[0][2]+bred[0][3];
    pcontr[2*blockIdx.x + 1] = bred[1][0]+bred[1][1]+bred[1][2]+bred[1][3];
  }
}

// ---------------- final reduction of partials + scalars ----------------
__global__ __launch_bounds__(256) void finalize_kernel(const float* __restrict__ pcontr,
                                                       const float* __restrict__ pdiv,
                                                       float* __restrict__ tail) {
  __shared__ float red[2][4];
  const int tid = threadIdx.x, lane = tid & 63, w = tid >> 6;
  float ls = 0.f, lt = 0.f;
  for (int k = tid; k < 2048; k += 256) { ls += pcontr[2*k]; lt += pcontr[2*k + 1]; }
  ls = wave_reduce_sum(ls);
  lt = wave_reduce_sum(lt);
  if (lane == 0) { red[0][w] = ls; red[1][w] = lt; }
  __syncthreads();
  if (tid == 0) {
    float sspec = red[0][0]+red[0][1]+red[0][2]+red[0][3];
    float sspat = red[1][0]+red[1][1]+red[1][2]+red[1][3];
    float dspec = 0.f, dspat = 0.f;
    for (int k = 0; k < 8; ++k) { dspec += pdiv[k]; dspat += pdiv[8+k]; }
    float loss_spec = -(sspec / (float)(B_*H_*N_));
    float loss_spat = -(sspat / (float)(B_*H_*N_));
    float denom = (float)(H_*M_*(M_-1)) + 1e-6f;
    tail[0] = 0.5f*(loss_spec + loss_spat);
    tail[1] = 0.01f * (dspec/denom + dspat/denom);
  }
}

extern "C" void kernel_launch(void* const* d_in, const int* in_sizes, int n_in,
                              void* d_out, int out_size, void* d_ws, size_t ws_size,
                              hipStream_t stream) {
  const float* x       = (const float*)d_in[0];
  const float* W_qkv   = (const float*)d_in[1];
  const float* W_proj  = (const float*)d_in[2];
  const float* b_proj  = (const float*)d_in[3];
  const float* W_rspec = (const float*)d_in[4];
  const float* b_rspec = (const float*)d_in[5];
  const float* W_rspat = (const float*)d_in[6];
  const float* b_rspat = (const float*)d_in[7];
  const float* K_spec  = (const float*)d_in[8];
  const float* K_spat  = (const float*)d_in[9];
  const float* W_tok   = (const float*)d_in[10];
  const float* b_tok   = (const float*)d_in[11];
  const float* W_prot  = (const float*)d_in[12];
  const float* b_prot  = (const float*)d_in[13];
  float* out = (float*)d_out;

  float* ws = (float*)d_ws;
  u16*   vb      = (u16*)ws;                        // bf16 [32768][512]  (8,388,608 f32 span)
  u16*   logits  = (u16*)(ws + 8388608);            // bf16 [32768][256]  (4,194,304 f32 span)
  u16*   pctx    = (u16*)(ws + 8388608);            // bf16 [1024][4096] overlays logits (consumed by topk first)
  float* pZ      = ws + 12582912;                   // 65,536 f32
  u16*   rb_spec = (u16*)(ws + 12648448);           // 2,097,152 f32 span
  u16*   rb_spat = (u16*)(ws + 14745600);
  u16*   xb      = (u16*)(ws + 16842752);           // bf16 [32768][512] (8,388,608 f32 span)
  u16*   Wqk     = (u16*)(ws + 25231360);           // [512 k][512 hd]
  u16*   Wt_v    = (u16*)(ws + 25362432);           // [512][512] — Wt_r contiguous after
  u16*   Wt_r    = (u16*)(ws + 25493504);           // [256][512]
  u16*   Wt_p    = (u16*)(ws + 25559040);           // [512][512]
  float* ctxb    = ws + 25690112;                   // [64][64][64] f32
  float* pnorm   = ws + 25952256;                   // 16,384 f32
  float* pcontr  = ws + 25968640;                   // 4,096 f32
  float* pdiv    = ws + 25972736;                   // 16 f32
  u16*   CWt     = (u16*)(ws + 25972752);           // bf16 [8][512][512]
  u16*   W2t     = (u16*)(ws + 27021328);           // bf16 [8][512][512]

  dim3 blk256(256);
  dim3 blk512(512);

  // 0. one-time bf16 conversions / weight transposes (merged)
  prep_all<<<2816, blk256, 0, stream>>>(x, xb, W_qkv, W_rspec, W_rspat, W_proj, Wqk, Wt_v, Wt_r, Wt_p);

  // 1. FUSED v + router GEMM: B = [Wt_v | Wt_r] (768 rows contiguous).
  //    cols 0..511 -> vb (bf16); cols 512..767 -> logits (bf16). 768 blocks = 3 exact CU rounds.
  gemm_bt<2><<<dim3(128,6), blk512, 0, stream>>>(xb, Wt_v, nullptr, vb, logits,
                                                 512, 512, 512, 256, 512, 0);
  // 2. top-k masked softmax (bf16 in/out)
  router_topk<<<2048, blk256, 0, stream>>>(logits, b_rspec, b_rspat, rb_spec, rb_spat);
  // 3. context via MFMA; partials bf16 (pctx overlays logits — consumed by topk already)
  context_mfma<<<1024, blk256, 0, stream>>>(rb_spec, rb_spat, K_spec, K_spat, vb, pctx, pZ);
  context_reduce<<<1024, blk256, 0, stream>>>(pctx, pZ, ctxb);
  // 4. CW = ctx @ Wp (per-batch 512x512), then W2 = Wq @ CW (small GEMM)
  cwt_kernel<<<512, blk256, 0, stream>>>(ctxb, Wt_p, CWt);
  gemm_bt<1><<<dim3(16,4), blk512, 0, stream>>>(CWt, Wqk, nullptr, W2t, nullptr,
                                                512, 512, 512, 0, 1 << 30, 0);
  // 5. losses (no atomics: per-block partials)
  protnorm_div<<<272, dim3(64), 0, stream>>>(K_spec, K_spat, W_prot, b_prot, pnorm, pdiv);
  contrastive_mfma<<<2048, blk256, 0, stream>>>(vb, rb_spec, rb_spat, W_tok, b_tok, pnorm, pcontr);
  // 6. out = x @ W2_b + bias (q and attn-output GEMMs collapsed); 512 blocks = 2 exact rounds
  gemm_bt<0><<<dim3(128,4), blk512, 0, stream>>>(xb, W2t, b_proj, out, nullptr,
                                                 512, 512, 512, 0, 1 << 30, 512*512);
  // 7. scalars
  finalize_kernel<<<1, blk256, 0, stream>>>(pcontr, pdiv, out + 16777216);
}

// Round 17
// 304.545 us; speedup vs baseline: 1.0701x; 1.0701x over previous
//
#include <hip/hip_runtime.h>
#include <math.h>

#define B_ 8
#define N_ 4096
#define C_ 512
#define H_ 8
#define D_ 64
#define M_ 16
#define BN_TOK (B_*N_)
#define TAU_ 0.1f

typedef short s8v __attribute__((ext_vector_type(8)));
typedef float f4v __attribute__((ext_vector_type(4)));
typedef unsigned short u16;

__device__ __forceinline__ float wave_reduce_sum(float v){
  #pragma unroll
  for (int o = 32; o > 0; o >>= 1) v += __shfl_xor(v, o);
  return v;
}

__device__ __forceinline__ unsigned short f2b(float f){
  unsigned int u = __float_as_uint(f);
  u += 0x7fffu + ((u >> 16) & 1u);           // RNE
  return (unsigned short)(u >> 16);
}

__device__ __forceinline__ float b2f(u16 b){
  return __uint_as_float(((unsigned int)b) << 16);
}

__device__ __forceinline__ s8v pack8(const float* f){
  s8v r;
  #pragma unroll
  for (int e = 0; e < 8; ++e) r[e] = (short)f2b(f[e]);
  return r;
}

// async 16B global -> LDS (linear dest: wave-uniform base + lane*16)
__device__ __forceinline__ void gload16(const u16* g, u16* l){
  __builtin_amdgcn_global_load_lds(
      (const __attribute__((address_space(1))) unsigned int*)g,
      (__attribute__((address_space(3))) unsigned int*)l, 16, 0, 0);
}

// ---------------- merged one-time conversions ----------------
__global__ __launch_bounds__(256) void prep_all(const float* __restrict__ x, u16* __restrict__ xb,
                                                const float* __restrict__ W_qkv,
                                                const float* __restrict__ W_rspec,
                                                const float* __restrict__ W_rspat,
                                                const float* __restrict__ W_proj,
                                                u16* __restrict__ Wqk,
                                                u16* __restrict__ Wt_v,
                                                u16* __restrict__ Wt_r,
                                                u16* __restrict__ Wt_p){
  const int bid = blockIdx.x;
  const int t = threadIdx.x;
  if (bid < 1024) {
    const int n8 = (BN_TOK*C_)/8;
    for (int i = bid * 256 + t; i < n8; i += 1024*256) {
      const float4* p = (const float4*)(x + (size_t)i * 8);
      float4 a = p[0], b = p[1];
      float f[8] = {a.x,a.y,a.z,a.w,b.x,b.y,b.z,b.w};
      *(s8v*)(xb + (size_t)i * 8) = pack8(f);
    }
    return;
  }
  if (bid < 1536) {                       // Wq k-major: Wqk[k][hd] = W_qkv[k][hd]
    const int k = bid - 1024;
    Wqk[(size_t)k*512 + t]       = f2b(W_qkv[(size_t)k*1536 + t]);
    Wqk[(size_t)k*512 + t + 256] = f2b(W_qkv[(size_t)k*1536 + t + 256]);
    return;
  }
  const int r = bid - 1536;
  const float* src; int ld, coff, n; u16* dst;
  if (r < 512)       { src = W_qkv;   ld = 1536; coff = 1024; n = r;        dst = Wt_v; }
  else if (r < 640)  { src = W_rspec; ld = 128;  coff = 0;    n = r - 512;  dst = Wt_r; }
  else if (r < 768)  { src = W_rspat; ld = 128;  coff = 0;    n = r - 640;  dst = Wt_r + 128*512; }
  else               { src = W_proj;  ld = 512;  coff = 0;    n = r - 768;  dst = Wt_p; }
  dst[(size_t)n*512 + t]       = f2b(src[(size_t)t*ld + coff + n]);
  dst[(size_t)n*512 + t + 256] = f2b(src[(size_t)(t+256)*ld + coff + n]);
}

// ====== bf16 GEMM, B pre-transposed: C[M,N] = A[M,K] * Bt[N,K]^T (+bias) ======
// BK=64 depth-2 counted-vmcnt pipeline, plain 2D grid. 128x128, 256 threads.
// MODE 0: f32 out (+bias). MODE 1: bf16 out.
// MODE 2: split — block cols < split -> bf16 C (ldc); >= split -> bf16 C2 (ldc2, col-split).
template<int MODE>
__global__ __launch_bounds__(256) void gemm_bt(const u16* __restrict__ A,
                                               const u16* __restrict__ Bt,
                                               const float* __restrict__ bias,
                                               void* __restrict__ C,
                                               u16* __restrict__ C2,
                                               int K, int lda, int ldc, int ldc2,
                                               int split, int bt_bstride) {
  __shared__ __align__(16) u16 Asm[2][2][128*32];   // [depth][khalf]
  __shared__ __align__(16) u16 Bsm[2][2][128*32];
  const int tid = threadIdx.x;
  const int lane = tid & 63, w = tid >> 6;
  const int bm = blockIdx.x * 128, bn = blockIdx.y * 128;

  const int lrow = lane >> 2;
  const int kch  = ((lane & 3) ^ ((lane >> 3) & 3)) << 3;   // pre-swizzled k-chunk

  const u16* Btb = Bt + (size_t)(bm >> 12) * bt_bstride;    // per-batch B (4096 rows/batch)
  const u16* Ag0 = A   + (size_t)(bm + w*16 + lrow) * lda + kch;
  const u16* Ag1 = Ag0 + (size_t)64 * lda;
  const u16* Bg0 = Btb + (size_t)(bn + w*16 + lrow) * K + kch;
  const u16* Bg1 = Bg0 + (size_t)64 * K;
  const int l0 = (w*16)*32, l1 = (w*16+64)*32;

  const int lm = lane & 15, lg = lane >> 4;
  const int w0 = (w >> 1) * 64, c0 = (w & 1) * 64;
  const int xs = (lg ^ ((lm >> 1) & 3)) << 3;               // read-side swizzle slot

  const int NSTEP = K >> 6;                                  // 64 k per step

  f4v acc[4][4];
  #pragma unroll
  for (int i = 0; i < 4; ++i)
    #pragma unroll
    for (int j = 0; j < 4; ++j) acc[i][j] = (f4v){0.f,0.f,0.f,0.f};

  #define STAGE(buf, tt)                                        \
    gload16(Ag0 + (tt)*64,      &Asm[buf][0][l0]);              \
    gload16(Ag1 + (tt)*64,      &Asm[buf][0][l1]);              \
    gload16(Ag0 + (tt)*64 + 32, &Asm[buf][1][l0]);              \
    gload16(Ag1 + (tt)*64 + 32, &Asm[buf][1][l1]);              \
    gload16(Bg0 + (tt)*64,      &Bsm[buf][0][l0]);              \
    gload16(Bg1 + (tt)*64,      &Bsm[buf][0][l1]);              \
    gload16(Bg0 + (tt)*64 + 32, &Bsm[buf][1][l0]);              \
    gload16(Bg1 + (tt)*64 + 32, &Bsm[buf][1][l1]);

  STAGE(0, 0)
  STAGE(1, 1)

  int cur = 0;
  for (int k = 0; k < NSTEP; ++k) {
    if (k < NSTEP - 1) asm volatile("s_waitcnt vmcnt(8)" ::: "memory");
    else               asm volatile("s_waitcnt vmcnt(0)" ::: "memory");
    __builtin_amdgcn_s_barrier();            // raw: no vmcnt(0) drain
    __builtin_amdgcn_sched_barrier(0);       // no ds_read hoist above barrier

    #pragma unroll
    for (int h = 0; h < 2; ++h) {
      s8v af[4], bf_[4];
      #pragma unroll
      for (int i = 0; i < 4; ++i) af[i]  = *(const s8v*)&Asm[cur][h][(w0 + 16*i + lm)*32 + xs];
      #pragma unroll
      for (int j = 0; j < 4; ++j) bf_[j] = *(const s8v*)&Bsm[cur][h][(c0 + 16*j + lm)*32 + xs];
      #pragma unroll
      for (int i = 0; i < 4; ++i)
        #pragma unroll
        for (int j = 0; j < 4; ++j)
          acc[i][j] = __builtin_amdgcn_mfma_f32_16x16x32_bf16(af[i], bf_[j], acc[i][j], 0, 0, 0);
    }

    __builtin_amdgcn_sched_barrier(0);       // reads complete before barrier in program order
    __builtin_amdgcn_s_barrier();            // all waves done reading buf[cur]
    if (k + 2 < NSTEP) {
      STAGE(cur, k + 2)
    }
    __builtin_amdgcn_sched_barrier(0);       // stages issue before next vmcnt counts them
    cur ^= 1;
  }
  #undef STAGE

  #pragma unroll
  for (int j = 0; j < 4; ++j) {
    const int col = bn + c0 + 16*j + lm;
    const float bj = (MODE == 0 && bias) ? bias[col] : 0.f;
    #pragma unroll
    for (int i = 0; i < 4; ++i) {
      const int row = bm + w0 + 16*i + 4*lg;
      #pragma unroll
      for (int r = 0; r < 4; ++r) {
        if (MODE == 2 && bn >= split)
          C2[(size_t)(row + r) * ldc2 + (col - split)] = f2b(acc[i][j][r]);
        else if (MODE == 1 || MODE == 2)
          ((u16*)C)[(size_t)(row + r) * ldc + col] = f2b(acc[i][j][r]);
        else
          ((float*)C)[(size_t)(row + r) * ldc + col] = acc[i][j][r] + bj;
      }
    }
  }
}

// ---------------- router top-k + masked softmax (bf16 logits in, bf16 r out) ----------------
__global__ __launch_bounds__(256) void router_topk(const u16* __restrict__ logits,
                            const float* __restrict__ b_rspec, const float* __restrict__ b_rspat,
                            u16* __restrict__ rb_spec, u16* __restrict__ rb_spat) {
  int t = blockIdx.x * blockDim.x + threadIdx.x;
  if (t >= BN_TOK * H_ * 2) return;
  int route = t & 1, h = (t >> 1) & 7, bn = t >> 4;
  int b = bn >> 12, n = bn & 4095;
  const u16* lg = logits + (size_t)bn*256 + route*128 + h*16;
  const float* bias = (route ? b_rspat : b_rspec) + h*16;
  float v[16];
  #pragma unroll
  for (int m=0;m<16;++m) v[m] = b2f(lg[m]) + bias[m];
  float m1=-1e30f, m2=-1e30f, m3=-1e30f;
  #pragma unroll
  for (int m=0;m<16;++m){
    float x=v[m];
    if (x>m1){m3=m2;m2=m1;m1=x;}
    else if (x>m2){m3=m2;m2=x;}
    else if (x>m3){m3=x;}
  }
  float S=0.f, Sm=0.f, e[16];
  #pragma unroll
  for (int m=0;m<16;++m){ e[m]=expf(v[m]-m1); S+=e[m]; if (v[m]>=m3) Sm+=e[m]; }
  float denom = fmaxf(Sm/S, 1e-6f);
  float inv = 1.f/(S*denom);
  size_t idx = (((size_t)b*H_ + h)*N_ + n)*16;
  u16* rb  = (route ? rb_spat : rb_spec) + idx;
  #pragma unroll
  for (int m=0;m<16;++m) {
    float val = (v[m] >= m3) ? e[m]*inv : 0.f;
    rb[m] = f2b(val);
  }
}

// ------- context via MFMA: per (b,h,chunk of 256 tokens); V from vb [tok][512]; pctx bf16 -------
__global__ __launch_bounds__(256) void context_mfma(const u16* __restrict__ rb_spec, const u16* __restrict__ rb_spat,
                               const float* __restrict__ K_spec, const float* __restrict__ K_spat,
                               const u16* __restrict__ vb, u16* __restrict__ pctx, float* __restrict__ pZ) {
  const int chunk = blockIdx.x & 15, bh = blockIdx.x >> 4;
  const int b = bh >> 3, h = bh & 7;
  const int tid = threadIdx.x;
  const int lane = tid & 63, w = tid >> 6;
  const int lm = lane & 15, lg = lane >> 4;

  __shared__ __align__(16) unsigned short Kc[64*32];   // B1: [d][k=32] swz4
  __shared__ __align__(16) unsigned short Rs[64*32];   // A1: [n][k=32] swz4
  __shared__ __align__(16) unsigned short Vt[64*64];   // A2: [e][n]    swz8
  __shared__ __align__(16) unsigned short Ps[64*64];   // B2: [d][n]    swz8
  __shared__ float Zs[256];

  {
    int d = tid & 63, c = tid >> 6;
    float f[8];
    #pragma unroll
    for (int u = 0; u < 8; ++u) {
      int k = c*8 + u;
      f[u] = (k < 16) ? K_spec[h*1024 + k*64 + d] : K_spat[h*1024 + (k-16)*64 + d];
    }
    *(s8v*)&Kc[d*32 + ((c ^ (d&3)) << 3)] = pack8(f);
  }

  const u16* rsg = rb_spec + ((size_t)bh*N_ + chunk*256)*16;
  const u16* rtg = rb_spat + ((size_t)bh*N_ + chunk*256)*16;
  const u16* vbase = vb + h*64;
  const size_t tokbase = (size_t)b*N_ + chunk*256;

  f4v acc2[4];
  #pragma unroll
  for (int j = 0; j < 4; ++j) acc2[j] = (f4v){0.f,0.f,0.f,0.f};
  float zreg[4] = {0.f,0.f,0.f,0.f};

  for (int t0 = 0; t0 < 4; ++t0) {
    __syncthreads();
    {
      int n = tid & 63, c = tid >> 6;
      const u16* src = (c < 2 ? rsg : rtg) + ((size_t)(t0*64 + n))*16 + (c&1)*8;
      *(s8v*)&Rs[n*32 + ((c ^ (n&3)) << 3)] = *(const s8v*)src;
    }
    {
      int n = tid & 63, eq = tid >> 6;
      const u16* src = vbase + (tokbase + t0*64 + n)*512 + eq*16;
      u16 f[16];
      *(s8v*)&f[0] = ((const s8v*)src)[0];
      *(s8v*)&f[8] = ((const s8v*)src)[1];
      #pragma unroll
      for (int u = 0; u < 16; ++u) {
        int e = eq*16 + u;
        Vt[e*64 + ((((n>>3) ^ (e&7)) << 3) | (n&7))] = f[u];
      }
    }
    __syncthreads();
    {
      s8v a1 = *(const s8v*)&Rs[(16*w + lm)*32 + ((lg ^ (lm&3)) << 3)];
      #pragma unroll
      for (int j = 0; j < 4; ++j) {
        s8v b1 = *(const s8v*)&Kc[(16*j + lm)*32 + ((lg ^ (lm&3)) << 3)];
        f4v c1 = (f4v){0.f,0.f,0.f,0.f};
        c1 = __builtin_amdgcn_mfma_f32_16x16x32_bf16(a1, b1, c1, 0, 0, 0);
        float p0 = expf(c1[0]), p1 = expf(c1[1]), p2 = expf(c1[2]), p3 = expf(c1[3]);
        float zz = p0 + p1 + p2 + p3;
        zz += __shfl_xor(zz, 16); zz += __shfl_xor(zz, 32);
        zreg[j] += zz;
        int d = 16*j + lm;
        int n0w = 16*w + 4*lg;
        Ps[d*64 + (((((n0w  )>>3) ^ (d&7)) << 3) | ((n0w  )&7))] = f2b(p0);
        Ps[d*64 + (((((n0w+1)>>3) ^ (d&7)) << 3) | ((n0w+1)&7))] = f2b(p1);
        Ps[d*64 + (((((n0w+2)>>3) ^ (d&7)) << 3) | ((n0w+2)&7))] = f2b(p2);
        Ps[d*64 + (((((n0w+3)>>3) ^ (d&7)) << 3) | ((n0w+3)&7))] = f2b(p3);
      }
    }
    __syncthreads();
    #pragma unroll
    for (int kb = 0; kb < 2; ++kb) {
      s8v a2 = *(const s8v*)&Vt[(16*w + lm)*64 + (((kb*4 + lg) ^ (lm&7)) << 3)];
      #pragma unroll
      for (int j = 0; j < 4; ++j) {
        s8v b2 = *(const s8v*)&Ps[(16*j + lm)*64 + (((kb*4 + lg) ^ (lm&7)) << 3)];
        acc2[j] = __builtin_amdgcn_mfma_f32_16x16x32_bf16(a2, b2, acc2[j], 0, 0, 0);
      }
    }
  }
  u16* pc = pctx + (size_t)(bh*16 + chunk)*4096;
  #pragma unroll
  for (int j = 0; j < 4; ++j) {
    #pragma unroll
    for (int r = 0; r < 4; ++r)
      pc[(16*w + 4*lg + r)*64 + 16*j + lm] = f2b(acc2[j][r]);
    if (lg == 0) Zs[w*64 + 16*j + lm] = zreg[j];
  }
  __syncthreads();
  if (tid < 64)
    pZ[(size_t)(bh*16 + chunk)*64 + tid] = Zs[tid] + Zs[64+tid] + Zs[128+tid] + Zs[192+tid];
}

// ---- reduce partials: ctx^T[e][d] = sum_c pctx / Z[d] (1 output/thread; pctx bf16) ----
__global__ __launch_bounds__(256) void context_reduce(const u16* __restrict__ pctx, const float* __restrict__ pZ,
                              float* __restrict__ ctx) {
  const int gid = blockIdx.x * 256 + threadIdx.x;
  const int bh = gid >> 12, e = (gid >> 6) & 63, d = gid & 63;
  float z = 0.f, s = 0.f;
  for (int c = 0; c < 16; ++c) {
    z += pZ[(size_t)(bh*16 + c)*64 + d];
    s += b2f(pctx[(size_t)(bh*16 + c)*4096 + e*64 + d]);
  }
  ctx[(size_t)bh*4096 + e*64 + d] = s / z;
}

// ---- CW precompute: CWt[b][c][h*64+d] = sum_e ctx^T[bh][e][d] * Wp[h*64+e][c] ----
__global__ __launch_bounds__(256) void cwt_kernel(const float* __restrict__ ctx, const u16* __restrict__ Wt_p,
                                                  u16* __restrict__ CWt) {
  const int bh = blockIdx.x >> 3, oct = blockIdx.x & 7;
  const int b = bh >> 3, h = bh & 7;
  const int tid = threadIdx.x;
  __shared__ float ctxS[64*64];       // [e][d]
  __shared__ u16 WsL[64*64];          // [c_local][e]
  {
    int e = tid >> 2, dq = tid & 3;
    const float4* src = (const float4*)(ctx + (size_t)bh*4096 + e*64 + dq*16);
    float4* dst = (float4*)(ctxS + e*64 + dq*16);
    dst[0] = src[0]; dst[1] = src[1]; dst[2] = src[2]; dst[3] = src[3];
  }
  const int c0 = oct * 64;
  {
    int cl = tid >> 2, eq = tid & 3;
    const s8v* src = (const s8v*)(Wt_p + (size_t)(c0 + cl)*512 + h*64 + eq*16);
    *(s8v*)&WsL[cl*64 + eq*16]     = src[0];
    *(s8v*)&WsL[cl*64 + eq*16 + 8] = src[1];
  }
  __syncthreads();
  const int d = tid & 63, cq = tid >> 6;
  for (int ci = 0; ci < 16; ++ci) {
    int cl = cq*16 + ci;
    float acc = 0.f;
    #pragma unroll
    for (int e = 0; e < 64; ++e)
      acc = fmaf(ctxS[e*64 + d], b2f(WsL[cl*64 + e]), acc);
    CWt[((size_t)b*512 + (c0 + cl))*512 + h*64 + d] = f2b(acc);
  }
}

// ---------------- normalized prototypes + diversity (merged grid) ----------------
__global__ __launch_bounds__(64) void protnorm_div(const float* __restrict__ K_spec, const float* __restrict__ K_spat,
                               const float* __restrict__ W_prot, const float* __restrict__ b_prot,
                               float* __restrict__ pnorm, float* __restrict__ pdiv) {
  const int bid = blockIdx.x;
  const int e = threadIdx.x;
  if (bid < 256) {
    int route = bid >> 7, hm = bid & 127;
    const float* Km = (route ? K_spat : K_spec) + hm*64;
    __shared__ float kv[64];
    kv[e] = Km[e];
    __syncthreads();
    float acc = b_prot[e];
    for (int dcol = 0; dcol < 64; ++dcol) acc = fmaf(kv[dcol], W_prot[dcol*64 + e], acc);
    float n2 = wave_reduce_sum(acc*acc);
    pnorm[(size_t)bid*64 + e] = acc / fmaxf(sqrtf(n2), 1e-12f);
    return;
  }
  const int db = bid - 256;                 // 0..15
  int route = db >> 3, h = db & 7;
  const float* Km = (route ? K_spat : K_spec) + h*16*64;
  float s = 0.f, selfsum = 0.f;
  for (int m = 0; m < 16; ++m) {
    float x = Km[m*64 + e];
    float n2 = wave_reduce_sum(x*x);
    float p = x / fmaxf(sqrtf(n2), 1e-6f);
    s += p; selfsum += p*p;
  }
  float off = wave_reduce_sum(s*s - selfsum);
  if (e == 0) pdiv[db] = off;
}

// ---------------- contrastive loss via MFMA (per-block partials, NO atomics; r from bf16) ----------------
__global__ __launch_bounds__(256) void contrastive_mfma(const u16* __restrict__ vb,
                                   const u16* __restrict__ rb_spec, const u16* __restrict__ rb_spat,
                                   const float* __restrict__ W_tok, const float* __restrict__ b_tok,
                                   const float* __restrict__ pnorm, float* __restrict__ pcontr) {
  const int tile = blockIdx.x & 255;
  const int h = blockIdx.x >> 8;
  const int t0 = tile * 128;
  const int b = t0 >> 12;
  const int n0 = t0 & 4095;
  const int tid = threadIdx.x;
  const int lane = tid & 63, w = tid >> 6;
  const int lm = lane & 15, lg = lane >> 4;

  __shared__ __align__(16) unsigned short Usm[128*72];   // V / T / S overlay (18 KB)
  __shared__ __align__(16) unsigned short Wsm[64*72];
  __shared__ __align__(16) unsigned short Psm[32*72];
  __shared__ float nrmS[128];
  __shared__ float btkS[64];
  __shared__ float bred[2][4];
  float* Uf = (float*)Usm;                               // S view: row stride 36 f32

  {
    const int vr = tid >> 1, vh = tid & 1;
    const u16* vg = vb + (size_t)(b*N_ + n0 + vr)*512 + h*64 + vh*32;
    #pragma unroll
    for (int c = 0; c < 4; ++c) *(s8v*)&Usm[vr*72 + vh*32 + c*8] = ((const s8v*)vg)[c];
  }
  {
    const int e = tid & 63, kh = tid >> 6;
    float f[16];
    #pragma unroll
    for (int rr = 0; rr < 16; ++rr) f[rr] = W_tok[(size_t)(kh*16+rr)*64 + e];
    *(s8v*)&Wsm[e*72 + kh*16]     = pack8(&f[0]);
    *(s8v*)&Wsm[e*72 + kh*16 + 8] = pack8(&f[8]);
  }
  if (tid < 128) {
    const int proto = tid >> 2, q4 = tid & 3;
    const int src = (proto < 16) ? (h*16 + proto) : (128 + h*16 + (proto-16));
    const float* pg = pnorm + (size_t)src*64 + q4*16;
    float f[16];
    #pragma unroll
    for (int i = 0; i < 4; ++i) {
      float4 v4 = ((const float4*)pg)[i];
      f[4*i]=v4.x; f[4*i+1]=v4.y; f[4*i+2]=v4.z; f[4*i+3]=v4.w;
    }
    *(s8v*)&Psm[proto*72 + q4*16]     = pack8(&f[0]);
    *(s8v*)&Psm[proto*72 + q4*16 + 8] = pack8(&f[8]);
  }
  if (tid < 64) btkS[tid] = b_tok[tid];
  __syncthreads();

  f4v acc[2][4];
  #pragma unroll
  for (int i=0;i<2;++i)
    #pragma unroll
    for (int j=0;j<4;++j) acc[i][j] = (f4v){0.f,0.f,0.f,0.f};
  {
    s8v bf0[4], bf1[4];
    #pragma unroll
    for (int j=0;j<4;++j) {
      bf0[j] = *(const s8v*)&Wsm[(j*16+lm)*72 + lg*8];
      bf1[j] = *(const s8v*)&Wsm[(j*16+lm)*72 + 32 + lg*8];
    }
    #pragma unroll
    for (int i=0;i<2;++i) {
      s8v af0 = *(const s8v*)&Usm[(w*32+16*i+lm)*72 + lg*8];
      s8v af1 = *(const s8v*)&Usm[(w*32+16*i+lm)*72 + 32 + lg*8];
      #pragma unroll
      for (int j=0;j<4;++j) {
        acc[i][j] = __builtin_amdgcn_mfma_f32_16x16x32_bf16(af0, bf0[j], acc[i][j], 0, 0, 0);
        acc[i][j] = __builtin_amdgcn_mfma_f32_16x16x32_bf16(af1, bf1[j], acc[i][j], 0, 0, 0);
      }
    }
  }
  #pragma unroll
  for (int i=0;i<2;++i) {
    #pragma unroll
    for (int r=0;r<4;++r) {
      float s = 0.f;
      #pragma unroll
      for (int j=0;j<4;++j) {
        float val = acc[i][j][r] + btkS[j*16+lm];
        acc[i][j][r] = val;
        s += val*val;
      }
      s += __shfl_xor(s,1); s += __shfl_xor(s,2); s += __shfl_xor(s,4); s += __shfl_xor(s,8);
      if (lm == 0) nrmS[w*32 + 16*i + lg*4 + r] = s;
    }
  }
  #pragma unroll
  for (int i=0;i<2;++i)
    #pragma unroll
    for (int j=0;j<4;++j)
      #pragma unroll
      for (int r=0;r<4;++r)
        Usm[(w*32+16*i+lg*4+r)*72 + j*16+lm] = f2b(acc[i][j][r]);
  __syncthreads();

  f4v acc2[2][2];
  #pragma unroll
  for (int i=0;i<2;++i)
    #pragma unroll
    for (int j=0;j<2;++j) acc2[i][j] = (f4v){0.f,0.f,0.f,0.f};
  {
    s8v bf0[2], bf1[2];
    #pragma unroll
    for (int j=0;j<2;++j) {
      bf0[j] = *(const s8v*)&Psm[(j*16+lm)*72 + lg*8];
      bf1[j] = *(const s8v*)&Psm[(j*16+lm)*72 + 32 + lg*8];
    }
    #pragma unroll
    for (int i=0;i<2;++i) {
      s8v af0 = *(const s8v*)&Usm[(w*32+16*i+lm)*72 + lg*8];
      s8v af1 = *(const s8v*)&Usm[(w*32+16*i+lm)*72 + 32 + lg*8];
      #pragma unroll
      for (int j=0;j<2;++j) {
        acc2[i][j] = __builtin_amdgcn_mfma_f32_16x16x32_bf16(af0, bf0[j], acc2[i][j], 0, 0, 0);
        acc2[i][j] = __builtin_amdgcn_mfma_f32_16x16x32_bf16(af1, bf1[j], acc2[i][j], 0, 0, 0);
      }
    }
  }
  #pragma unroll
  for (int i=0;i<2;++i)
    #pragma unroll
    for (int j=0;j<2;++j)
      #pragma unroll
      for (int r=0;r<4;++r)
        Uf[(w*32+16*i+lg*4+r)*36 + j*16+lm] = acc2[i][j][r];
  __syncthreads();

  float l = 0.f;
  {
    const int tt = tid >> 1, route = tid & 1;
    float inv = 1.f / fmaxf(sqrtf(nrmS[tt]), 1e-12f);
    const u16* rg = (route ? rb_spat : rb_spec) + (((size_t)b*H_ + h)*N_ + n0 + tt)*16;
    float s0[16];
    #pragma unroll
    for (int m=0;m<16;++m) s0[m] = Uf[tt*36 + route*16 + m]*inv;
    float pos = 0.f, mx = -1e30f;
    #pragma unroll
    for (int m=0;m<16;++m) {
      pos += s0[m]*b2f(rg[m]);
      mx = fmaxf(mx, s0[m]);
    }
    float z = 0.f;
    #pragma unroll
    for (int m=0;m<16;++m) z += expf((s0[m]-mx)/TAU_);
    l = pos/TAU_ - (mx/TAU_ + logf(z));
  }
  float lspec = (tid & 1) ? 0.f : l;
  float lspat = (tid & 1) ? l : 0.f;
  lspec = wave_reduce_sum(lspec);
  lspat = wave_reduce_sum(lspat);
  if (lane == 0) { bred[0][w]=lspec; bred[1][w]=lspat; }
  __syncthreads();
  if (tid == 0) {
    pcontr[2*blockIdx.x]     = bred[0][0]+bred[0][1]+bred[0][2]+bred[0][3];
    pcontr[2*blockIdx.x + 1] = bred[1][0]+bred[1][1]+bred[1][2]+bred[1][3];
  }
}

// ---------------- final reduction of partials + scalars ----------------
__global__ __launch_bounds__(256) void finalize_kernel(const float* __restrict__ pcontr,
                                                       const float* __restrict__ pdiv,
                                                       float* __restrict__ tail) {
  __shared__ float red[2][4];
  const int tid = threadIdx.x, lane = tid & 63, w = tid >> 6;
  float ls = 0.f, lt = 0.f;
  for (int k = tid; k < 2048; k += 256) { ls += pcontr[2*k]; lt += pcontr[2*k + 1]; }
  ls = wave_reduce_sum(ls);
  lt = wave_reduce_sum(lt);
  if (lane == 0) { red[0][w] = ls; red[1][w] = lt; }
  __syncthreads();
  if (tid == 0) {
    float sspec = red[0][0]+red[0][1]+red[0][2]+red[0][3];
    float sspat = red[1][0]+red[1][1]+red[1][2]+red[1][3];
    float dspec = 0.f, dspat = 0.f;
    for (int k = 0; k < 8; ++k) { dspec += pdiv[k]; dspat += pdiv[8+k]; }
    float loss_spec = -(sspec / (float)(B_*H_*N_));
    float loss_spat = -(sspat / (float)(B_*H_*N_));
    float denom = (float)(H_*M_*(M_-1)) + 1e-6f;
    tail[0] = 0.5f*(loss_spec + loss_spat);
    tail[1] = 0.01f * (dspec/denom + dspat/denom);
  }
}

extern "C" void kernel_launch(void* const* d_in, const int* in_sizes, int n_in,
                              void* d_out, int out_size, void* d_ws, size_t ws_size,
                              hipStream_t stream) {
  const float* x       = (const float*)d_in[0];
  const float* W_qkv   = (const float*)d_in[1];
  const float* W_proj  = (const float*)d_in[2];
  const float* b_proj  = (const float*)d_in[3];
  const float* W_rspec = (const float*)d_in[4];
  const float* b_rspec = (const float*)d_in[5];
  const float* W_rspat = (const float*)d_in[6];
  const float* b_rspat = (const float*)d_in[7];
  const float* K_spec  = (const float*)d_in[8];
  const float* K_spat  = (const float*)d_in[9];
  const float* W_tok   = (const float*)d_in[10];
  const float* b_tok   = (const float*)d_in[11];
  const float* W_prot  = (const float*)d_in[12];
  const float* b_prot  = (const float*)d_in[13];
  float* out = (float*)d_out;

  float* ws = (float*)d_ws;
  u16*   vb      = (u16*)ws;                        // bf16 [32768][512]  (8,388,608 f32 span)
  u16*   logits  = (u16*)(ws + 8388608);            // bf16 [32768][256]  (4,194,304 f32 span)
  u16*   pctx    = (u16*)(ws + 8388608);            // bf16 [1024][4096] overlays logits (consumed by topk first)
  float* pZ      = ws + 12582912;                   // 65,536 f32
  u16*   rb_spec = (u16*)(ws + 12648448);           // 2,097,152 f32 span
  u16*   rb_spat = (u16*)(ws + 14745600);
  u16*   xb      = (u16*)(ws + 16842752);           // bf16 [32768][512] (8,388,608 f32 span)
  u16*   Wqk     = (u16*)(ws + 25231360);           // [512 k][512 hd]
  u16*   Wt_v    = (u16*)(ws + 25362432);           // [512][512] — Wt_r contiguous after
  u16*   Wt_r    = (u16*)(ws + 25493504);           // [256][512]
  u16*   Wt_p    = (u16*)(ws + 25559040);           // [512][512]
  float* ctxb    = ws + 25690112;                   // [64][64][64] f32
  float* pnorm   = ws + 25952256;                   // 16,384 f32
  float* pcontr  = ws + 25968640;                   // 4,096 f32
  float* pdiv    = ws + 25972736;                   // 16 f32
  u16*   CWt     = (u16*)(ws + 25972752);           // bf16 [8][512][512]
  u16*   W2t     = (u16*)(ws + 27021328);           // bf16 [8][512][512]

  dim3 blk256(256);

  // 0. one-time bf16 conversions / weight transposes (merged)
  prep_all<<<2816, blk256, 0, stream>>>(x, xb, W_qkv, W_rspec, W_rspat, W_proj, Wqk, Wt_v, Wt_r, Wt_p);

  // 1. FUSED v + router GEMM: B = [Wt_v | Wt_r] (768 rows contiguous).
  //    cols 0..511 -> vb (bf16); cols 512..767 -> logits (bf16).
  gemm_bt<2><<<dim3(256,6), blk256, 0, stream>>>(xb, Wt_v, nullptr, vb, logits,
                                                 512, 512, 512, 256, 512, 0);
  // 2. top-k masked softmax (bf16 in/out)
  router_topk<<<2048, blk256, 0, stream>>>(logits, b_rspec, b_rspat, rb_spec, rb_spat);
  // 3. context via MFMA; partials bf16 (pctx overlays logits — consumed by topk already)
  context_mfma<<<1024, blk256, 0, stream>>>(rb_spec, rb_spat, K_spec, K_spat, vb, pctx, pZ);
  context_reduce<<<1024, blk256, 0, stream>>>(pctx, pZ, ctxb);
  // 4. CW = ctx @ Wp (per-batch 512x512), then W2 = Wq @ CW (small GEMM)
  cwt_kernel<<<512, blk256, 0, stream>>>(ctxb, Wt_p, CWt);
  gemm_bt<1><<<dim3(32,4), blk256, 0, stream>>>(CWt, Wqk, nullptr, W2t, nullptr,
                                                512, 512, 512, 0, 1 << 30, 0);
  // 5. losses (no atomics: per-block partials)
  protnorm_div<<<272, dim3(64), 0, stream>>>(K_spec, K_spat, W_prot, b_prot, pnorm, pdiv);
  contrastive_mfma<<<2048, blk256, 0, stream>>>(vb, rb_spec, rb_spat, W_tok, b_tok, pnorm, pcontr);
  // 6. out = x @ W2_b + bias  (q and attn-output GEMMs collapsed)
  gemm_bt<0><<<dim3(256,4), blk256, 0, stream>>>(xb, W2t, b_proj, out, nullptr,
                                                 512, 512, 512, 0, 1 << 30, 512*512);
  // 7. scalars
  finalize_kernel<<<1, blk256, 0, stream>>>(pcontr, pdiv, out + 16777216);
}